// Round 1
// baseline (2396.426 us; speedup 1.0000x reference)
//
#include <hip/hip_runtime.h>
#include <hip/hip_bf16.h>
#include <cmath>

#define RPB      32        // rows per fine bucket
#define FB_CAP   1280      // fine-bucket slot capacity (mean 1024, +8 sigma)
#define SB_SHIFT 11        // 2048 rows per super-bucket
#define NSB_MAX  64
#define TILE     2048      // edges per binning tile
#define CH_PER_SB 34       // pass-2 chunks per super-bucket (cap/34 <= TILE)

typedef __attribute__((ext_vector_type(8))) short short8;
typedef __attribute__((ext_vector_type(4))) float floatx4;

__device__ __forceinline__ unsigned short f2bf(float f) {
    unsigned int u = __float_as_uint(f);
    u += 0x7FFFu + ((u >> 16) & 1u);   // RNE
    return (unsigned short)(u >> 16);
}

// native LDS float atomic add (relaxed, wg scope, result unused -> ds_add_f32)
__device__ __forceinline__ void lds_fadd(float* p, float v) {
    __hip_atomic_fetch_add(p, v, __ATOMIC_RELAXED, __HIP_MEMORY_SCOPE_WORKGROUP);
}

// ---------------- MFMA GEMM: Yb[n][o] = bf16( x@W^T + b ) --------------------
__global__ __launch_bounds__(256) void gemm_mfma_kernel(
    const float* __restrict__ x, const float* __restrict__ W,
    const float* __restrict__ b, unsigned short* __restrict__ Yb, int N)
{
    __shared__ unsigned short Wb[128][136];
    __shared__ unsigned short Xb[64][136];
    const int t    = threadIdx.x;
    const int wave = t >> 6;
    const int lane = t & 63;
    const int col  = lane & 15;
    const int quad = lane >> 4;
    const int rowbase = blockIdx.x * 64;

#pragma unroll
    for (int i = 0; i < 16; ++i) {
        const int idx = t + 256 * i;
        const int o = idx >> 5, k4 = (idx & 31) * 4;
        const float4 v = *(const float4*)&W[(size_t)idx * 4];
        Wb[o][k4 + 0] = f2bf(v.x); Wb[o][k4 + 1] = f2bf(v.y);
        Wb[o][k4 + 2] = f2bf(v.z); Wb[o][k4 + 3] = f2bf(v.w);
    }
#pragma unroll
    for (int i = 0; i < 8; ++i) {
        const int idx = t + 256 * i;
        const int row = idx >> 5, k4 = (idx & 31) * 4;
        const int gr = rowbase + row;
        float4 v = make_float4(0.f, 0.f, 0.f, 0.f);
        if (gr < N) v = *(const float4*)&x[(size_t)gr * 128 + k4];
        Xb[row][k4 + 0] = f2bf(v.x); Xb[row][k4 + 1] = f2bf(v.y);
        Xb[row][k4 + 2] = f2bf(v.z); Xb[row][k4 + 3] = f2bf(v.w);
    }
    __syncthreads();

    float bias[8];
#pragma unroll
    for (int nt = 0; nt < 8; ++nt) bias[nt] = b[nt * 16 + col];

    floatx4 acc[8] = {};
    const int mrow = wave * 16;
#pragma unroll
    for (int k0 = 0; k0 < 128; k0 += 32) {
        const short8 a = *(const short8*)&Xb[mrow + col][k0 + quad * 8];
#pragma unroll
        for (int nt = 0; nt < 8; ++nt) {
            const short8 bf = *(const short8*)&Wb[nt * 16 + col][k0 + quad * 8];
            acc[nt] = __builtin_amdgcn_mfma_f32_16x16x32_bf16(a, bf, acc[nt], 0, 0, 0);
        }
    }
#pragma unroll
    for (int nt = 0; nt < 8; ++nt) {
#pragma unroll
        for (int reg = 0; reg < 4; ++reg) {
            const int gr = rowbase + mrow + quad * 4 + reg;
            if (gr < N)
                Yb[(size_t)gr * 128 + nt * 16 + col] = f2bf(acc[nt][reg] + bias[nt]);
        }
    }
}

// ---------------- P0: init cursors -------------------------------------------
__global__ __launch_bounds__(256) void init_cursor_kernel(
    int* __restrict__ cursor1, int* __restrict__ cursor2, int SB_CAP, int NB)
{
    const int i = blockIdx.x * blockDim.x + threadIdx.x;
    if (i < NSB_MAX) cursor1[i] = i * SB_CAP;
    if (i < NB)      cursor2[i] = i * FB_CAP;
}

// ---------------- P1: tile sort by super-bucket, grouped writes --------------
// key layout in pairs1: .x = ((row & 2047) << 17) | col  (super-bucket implied
// by slot region), .y = val bits.
__global__ __launch_bounds__(256) void pass1_kernel(
    const int* __restrict__ rows, const int* __restrict__ cols,
    const float* __restrict__ vals, int* __restrict__ cursor1,
    int2* __restrict__ pairs1, int E)
{
    __shared__ int2 sbuf[TILE];
    __shared__ unsigned char sbin[TILE];
    __shared__ unsigned short perm[TILE];
    __shared__ int hist[NSB_MAX], off[NSB_MAX], gbase[NSB_MAX], cur[NSB_MAX];
    const int t  = threadIdx.x;
    const int lo = blockIdx.x * TILE;
    const int cnt = min(TILE, E - lo);

    if (t < NSB_MAX) hist[t] = 0;
    __syncthreads();
    for (int i = t; i < cnt; i += 256) {
        const int   r = rows[lo + i];
        const int   c = cols[lo + i];
        const float v = vals[lo + i];
        sbuf[i] = make_int2(((r & 2047) << 17) | c, __float_as_int(v));
        const int bb = r >> SB_SHIFT;
        sbin[i] = (unsigned char)bb;
        atomicAdd(&hist[bb], 1);
    }
    __syncthreads();
    if (t == 0) {
        int run = 0;
        for (int k = 0; k < NSB_MAX; ++k) { off[k] = run; cur[k] = run; run += hist[k]; }
    }
    __syncthreads();
    if (t < NSB_MAX && hist[t] > 0) gbase[t] = atomicAdd(&cursor1[t], hist[t]);
    __syncthreads();
    for (int i = t; i < cnt; i += 256) {
        const int pos = atomicAdd(&cur[sbin[i]], 1);
        perm[pos] = (unsigned short)i;
    }
    __syncthreads();
    for (int i = t; i < cnt; i += 256) {
        const int src = perm[i];
        const int bb  = sbin[src];
        pairs1[gbase[bb] + (i - off[bb])] = sbuf[src];
    }
}

// ---------------- P2: chunk sort by fine bucket, grouped writes --------------
__global__ __launch_bounds__(256) void pass2_kernel(
    const int* __restrict__ cursor1, int* __restrict__ cursor2,
    const int2* __restrict__ pairs1, int2* __restrict__ pairs2, int SB_CAP)
{
    __shared__ int2 sbuf[TILE];
    __shared__ unsigned short perm[TILE];
    __shared__ int hist[64], off[64], gbase[64], cur[64];
    const int t   = threadIdx.x;
    const int sb  = blockIdx.x / CH_PER_SB;
    const int ch  = blockIdx.x % CH_PER_SB;
    const int base = sb * SB_CAP;
    const int scnt = cursor1[sb] - base;
    const int csz  = (scnt + CH_PER_SB - 1) / CH_PER_SB;
    const int lo   = ch * csz;
    const int cnt  = max(0, min(csz, scnt - lo));

    if (t < 64) hist[t] = 0;
    __syncthreads();
    for (int i = t; i < cnt; i += 256) {
        const int2 p = pairs1[base + lo + i];
        sbuf[i] = p;
        atomicAdd(&hist[(unsigned)p.x >> 22], 1);   // fine bucket within sb
    }
    __syncthreads();
    if (t == 0) {
        int run = 0;
        for (int k = 0; k < 64; ++k) { off[k] = run; cur[k] = run; run += hist[k]; }
    }
    __syncthreads();
    if (t < 64 && hist[t] > 0)
        gbase[t] = atomicAdd(&cursor2[sb * 64 + t], hist[t]);
    __syncthreads();
    for (int i = t; i < cnt; i += 256) {
        const int pos = atomicAdd(&cur[(unsigned)sbuf[i].x >> 22], 1);
        perm[pos] = (unsigned short)i;
    }
    __syncthreads();
    for (int i = t; i < cnt; i += 256) {
        const int2 p = sbuf[perm[i]];
        const int bb = (unsigned)p.x >> 22;
        // keep ((row&31)<<17)|col for sortgather
        pairs2[gbase[bb] + (i - off[bb])] = make_int2(p.x & 0x3FFFFF, p.y);
    }
}

// ---------------- P3: scan bucket edges, LDS fp32 accumulate, ELU ------------
// No in-bucket sort: each wave scans a quarter of the bucket's edges and
// ds_add_f32's v*Y[col] into accum[row][128]. Waves are balanced by edge
// count; the counting-sort (hist/prefix/scatter/rowtick) is gone.
__global__ __launch_bounds__(256) void sortgather_kernel(
    const int* __restrict__ cursor2, const int2* __restrict__ pairs2,
    const unsigned int* __restrict__ Yu, float* __restrict__ out, int N)
{
    __shared__ __align__(16) int2 sbuf[FB_CAP];
    __shared__ float accum[RPB * 128];
    const int b    = blockIdx.x;
    const int t    = threadIdx.x;
    const int w    = t >> 6;
    const int lane = t & 63;
    const int slot = b * FB_CAP;
    int cnt = cursor2[b] - slot;
    if (cnt > FB_CAP) cnt = FB_CAP;

    // zero accumulators (16 KB)
    {
        float4* a4 = (float4*)accum;
#pragma unroll
        for (int i = 0; i < RPB * 32 / 256; ++i)
            a4[t + 256 * i] = make_float4(0.f, 0.f, 0.f, 0.f);
    }
    // stage pairs (2 pairs / 16B per load, coalesced)
    {
        const int4* src4 = (const int4*)(pairs2 + slot);
        int4* dst4 = (int4*)sbuf;
        const int nv4 = (cnt + 1) >> 1;
        for (int i = t; i < nv4; i += 256) dst4[i] = src4[i];
    }
    __syncthreads();

    // this wave's edge range (even start keeps int4 LDS reads 16B-aligned)
    int q = (cnt + 3) >> 2;
    q = (q + 1) & ~1;
    const int lo = w * q;
    const int hi = min(lo + q, cnt);
    const int l2 = 2 * lane;

    int j = lo;
    for (; j + 4 <= hi; j += 4) {
        const int4 pA = *(const int4*)&sbuf[j];
        const int4 pB = *(const int4*)&sbuf[j + 2];
        // issue all 4 gathers before any use
        const unsigned yA0 = Yu[((unsigned)(pA.x & 0x1FFFF) << 6) + lane];
        const unsigned yA1 = Yu[((unsigned)(pA.z & 0x1FFFF) << 6) + lane];
        const unsigned yB0 = Yu[((unsigned)(pB.x & 0x1FFFF) << 6) + lane];
        const unsigned yB1 = Yu[((unsigned)(pB.z & 0x1FFFF) << 6) + lane];
        {
            float* a = &accum[((unsigned)pA.x >> 17) * 128 + l2];
            const float v = __int_as_float(pA.y);
            lds_fadd(a,     v * __uint_as_float(yA0 << 16));
            lds_fadd(a + 1, v * __uint_as_float(yA0 & 0xFFFF0000u));
        }
        {
            float* a = &accum[((unsigned)pA.z >> 17) * 128 + l2];
            const float v = __int_as_float(pA.w);
            lds_fadd(a,     v * __uint_as_float(yA1 << 16));
            lds_fadd(a + 1, v * __uint_as_float(yA1 & 0xFFFF0000u));
        }
        {
            float* a = &accum[((unsigned)pB.x >> 17) * 128 + l2];
            const float v = __int_as_float(pB.y);
            lds_fadd(a,     v * __uint_as_float(yB0 << 16));
            lds_fadd(a + 1, v * __uint_as_float(yB0 & 0xFFFF0000u));
        }
        {
            float* a = &accum[((unsigned)pB.z >> 17) * 128 + l2];
            const float v = __int_as_float(pB.w);
            lds_fadd(a,     v * __uint_as_float(yB1 << 16));
            lds_fadd(a + 1, v * __uint_as_float(yB1 & 0xFFFF0000u));
        }
    }
    for (; j < hi; ++j) {
        const int2 p = sbuf[j];
        const unsigned y = Yu[((unsigned)(p.x & 0x1FFFF) << 6) + lane];
        float* a = &accum[((unsigned)p.x >> 17) * 128 + l2];
        const float v = __int_as_float(p.y);
        lds_fadd(a,     v * __uint_as_float(y << 16));
        lds_fadd(a + 1, v * __uint_as_float(y & 0xFFFF0000u));
    }
    __syncthreads();

    // ELU + coalesced store (float2 per thread)
    const int rowbase = b * RPB;
    for (int k = t; k < RPB * 64; k += 256) {
        const int row = k >> 6;
        const int gr  = rowbase + row;
        if (gr < N) {
            const float2 a = *(const float2*)&accum[k * 2];
            float2 o;
            o.x = a.x > 0.f ? a.x : expf(a.x) - 1.f;
            o.y = a.y > 0.f ? a.y : expf(a.y) - 1.f;
            *(float2*)&out[(size_t)gr * 128 + (k & 63) * 2] = o;
        }
    }
}

// ---------------- Fallback path (fp32, atomic scatter) -----------------------
__global__ __launch_bounds__(256) void gemm_bias_kernel(
    const float* __restrict__ x, const float* __restrict__ W,
    const float* __restrict__ b, float* __restrict__ Y, int N)
{
    __shared__ float Wt[128][130];
    const int tid  = threadIdx.x;
    const int wave = tid >> 6;
    const int lane = tid & 63;
    for (int i = tid; i < 128 * 128; i += 256) {
        const int o = i >> 7, k = i & 127;
        Wt[k][o] = W[i];
    }
    __syncthreads();
    const float2 bv = *(const float2*)&b[2 * lane];
    for (int row = blockIdx.x * 4 + wave; row < N; row += gridDim.x * 4) {
        float acc0 = 0.f, acc1 = 0.f;
        for (int k = 0; k < 128; ++k) {
            const float2 w = *(const float2*)&Wt[k][2 * lane];
            const float xv = x[(size_t)row * 128 + k];
            acc0 = fmaf(xv, w.x, acc0);
            acc1 = fmaf(xv, w.y, acc1);
        }
        float2 o2; o2.x = acc0 + bv.x; o2.y = acc1 + bv.y;
        *(float2*)&Y[(size_t)row * 128 + 2 * lane] = o2;
    }
}

__global__ __launch_bounds__(256) void scatter_kernel(
    const int* __restrict__ rows, const int* __restrict__ cols,
    const float* __restrict__ vals, const float* __restrict__ Y,
    float* __restrict__ out, int E)
{
    const long long gid = (long long)blockIdx.x * blockDim.x + threadIdx.x;
    const int wid  = (int)(gid >> 6);
    const int lane = threadIdx.x & 63;
    if (wid >= E) return;
    const int   r = rows[wid];
    const int   c = cols[wid];
    const float v = vals[wid];
    const float2 y = *(const float2*)&Y[(size_t)c * 128 + 2 * lane];
    float* po = &out[(size_t)r * 128 + 2 * lane];
    atomicAdd(po,     v * y.x);
    atomicAdd(po + 1, v * y.y);
}

__global__ __launch_bounds__(256) void elu_kernel(float* __restrict__ out, int n4)
{
    int i = blockIdx.x * blockDim.x + threadIdx.x;
    const int stride = gridDim.x * blockDim.x;
    float4* p = (float4*)out;
    for (; i < n4; i += stride) {
        float4 v = p[i];
        v.x = v.x > 0.f ? v.x : expf(v.x) - 1.f;
        v.y = v.y > 0.f ? v.y : expf(v.y) - 1.f;
        v.z = v.z > 0.f ? v.z : expf(v.z) - 1.f;
        v.w = v.w > 0.f ? v.w : expf(v.w) - 1.f;
        p[i] = v;
    }
}

// -----------------------------------------------------------------------------
extern "C" void kernel_launch(void* const* d_in, const int* in_sizes, int n_in,
                              void* d_out, int out_size, void* d_ws, size_t ws_size,
                              hipStream_t stream)
{
    const float* x    = (const float*)d_in[0];
    const float* W    = (const float*)d_in[1];
    const float* b    = (const float*)d_in[2];
    const int*   rows = (const int*)d_in[3];
    const int*   cols = (const int*)d_in[4];
    const float* vals = (const float*)d_in[5];
    float* out = (float*)d_out;

    const int N   = in_sizes[0] / 128;
    const int E   = in_sizes[3];
    const int NB  = (N + RPB - 1) / RPB;               // fine buckets
    const int NSB = (N + (1 << SB_SHIFT) - 1) >> SB_SHIFT;  // super-buckets

    // SB_CAP = mean + ~10 sigma, 64-aligned
    const int sb_mean = (E + NSB - 1) / NSB;
    int sbsig = 1; while (sbsig * sbsig < sb_mean) ++sbsig;
    const int SB_CAP = (sb_mean + 10 * sbsig + 63) & ~63;

    auto align256 = [](size_t v) { return (v + 255) & ~(size_t)255; };
    const size_t offPairs2 = 0;
    const size_t szPairs2  = (size_t)NB * FB_CAP * 8;
    const size_t offShared = align256(offPairs2 + szPairs2);   // pairs1 then Y
    const size_t szShared  = (size_t)NSB * SB_CAP * 8 > (size_t)N * 256
                           ? (size_t)NSB * SB_CAP * 8 : (size_t)N * 256;
    const size_t offCur1   = align256(offShared + szShared);
    const size_t offCur2   = align256(offCur1 + NSB_MAX * 4);
    const size_t need      = offCur2 + (size_t)NB * 4;

    const bool csr_ok = (need <= ws_size) && (NSB <= NSB_MAX) &&
                        ((long long)E <= (long long)NB * 1056) &&
                        (SB_CAP <= CH_PER_SB * TILE);

    if (csr_ok) {
        int2* pairs2        = (int2*)((char*)d_ws + offPairs2);
        int2* pairs1        = (int2*)((char*)d_ws + offShared);
        unsigned short* Yb  = (unsigned short*)((char*)d_ws + offShared);
        int*  cursor1       = (int*)((char*)d_ws + offCur1);
        int*  cursor2       = (int*)((char*)d_ws + offCur2);

        init_cursor_kernel<<<(NB + 255) / 256, 256, 0, stream>>>(cursor1, cursor2,
                                                                 SB_CAP, NB);
        pass1_kernel<<<(E + TILE - 1) / TILE, 256, 0, stream>>>(rows, cols, vals,
                                                                cursor1, pairs1, E);
        pass2_kernel<<<NSB * CH_PER_SB, 256, 0, stream>>>(cursor1, cursor2,
                                                          pairs1, pairs2, SB_CAP);
        // GEMM after pass2: Yb aliases pairs1 (dead now)
        gemm_mfma_kernel<<<(N + 63) / 64, 256, 0, stream>>>(x, W, b, Yb, N);
        sortgather_kernel<<<NB, 256, 0, stream>>>(cursor2, pairs2,
                                                  (const unsigned int*)Yb, out, N);
    } else {
        float* Y = (float*)d_ws;
        hipMemsetAsync(d_out, 0, (size_t)out_size * sizeof(float), stream);
        gemm_bias_kernel<<<512, 256, 0, stream>>>(x, W, b, Y, N);
        scatter_kernel<<<(E + 3) / 4, 256, 0, stream>>>(rows, cols, vals, Y, out, E);
        elu_kernel<<<1024, 256, 0, stream>>>(out, out_size / 4);
    }
}

// Round 2
// 317.172 us; speedup vs baseline: 7.5556x; 7.5556x over previous
//
#include <hip/hip_runtime.h>
#include <hip/hip_bf16.h>
#include <cmath>

#define RPB      32        // rows per fine bucket
#define FB_CAP   1280      // fine-bucket slot capacity (mean 1024, +8 sigma)
#define SB_SHIFT 11        // 2048 rows per super-bucket
#define NSB_MAX  64
#define TILE     2048      // edges per binning tile
#define CH_PER_SB 34       // pass-2 chunks per super-bucket (cap/34 <= TILE)

typedef __attribute__((ext_vector_type(8))) short short8;
typedef __attribute__((ext_vector_type(4))) float floatx4;

__device__ __forceinline__ unsigned short f2bf(float f) {
    unsigned int u = __float_as_uint(f);
    u += 0x7FFFu + ((u >> 16) & 1u);   // RNE
    return (unsigned short)(u >> 16);
}

// ---------------- MFMA GEMM: Yb[n][o] = bf16( x@W^T + b ) --------------------
__global__ __launch_bounds__(256) void gemm_mfma_kernel(
    const float* __restrict__ x, const float* __restrict__ W,
    const float* __restrict__ b, unsigned short* __restrict__ Yb, int N)
{
    __shared__ unsigned short Wb[128][136];
    __shared__ unsigned short Xb[64][136];
    const int t    = threadIdx.x;
    const int wave = t >> 6;
    const int lane = t & 63;
    const int col  = lane & 15;
    const int quad = lane >> 4;
    const int rowbase = blockIdx.x * 64;

#pragma unroll
    for (int i = 0; i < 16; ++i) {
        const int idx = t + 256 * i;
        const int o = idx >> 5, k4 = (idx & 31) * 4;
        const float4 v = *(const float4*)&W[(size_t)idx * 4];
        Wb[o][k4 + 0] = f2bf(v.x); Wb[o][k4 + 1] = f2bf(v.y);
        Wb[o][k4 + 2] = f2bf(v.z); Wb[o][k4 + 3] = f2bf(v.w);
    }
#pragma unroll
    for (int i = 0; i < 8; ++i) {
        const int idx = t + 256 * i;
        const int row = idx >> 5, k4 = (idx & 31) * 4;
        const int gr = rowbase + row;
        float4 v = make_float4(0.f, 0.f, 0.f, 0.f);
        if (gr < N) v = *(const float4*)&x[(size_t)gr * 128 + k4];
        Xb[row][k4 + 0] = f2bf(v.x); Xb[row][k4 + 1] = f2bf(v.y);
        Xb[row][k4 + 2] = f2bf(v.z); Xb[row][k4 + 3] = f2bf(v.w);
    }
    __syncthreads();

    float bias[8];
#pragma unroll
    for (int nt = 0; nt < 8; ++nt) bias[nt] = b[nt * 16 + col];

    floatx4 acc[8] = {};
    const int mrow = wave * 16;
#pragma unroll
    for (int k0 = 0; k0 < 128; k0 += 32) {
        const short8 a = *(const short8*)&Xb[mrow + col][k0 + quad * 8];
#pragma unroll
        for (int nt = 0; nt < 8; ++nt) {
            const short8 bf = *(const short8*)&Wb[nt * 16 + col][k0 + quad * 8];
            acc[nt] = __builtin_amdgcn_mfma_f32_16x16x32_bf16(a, bf, acc[nt], 0, 0, 0);
        }
    }
#pragma unroll
    for (int nt = 0; nt < 8; ++nt) {
#pragma unroll
        for (int reg = 0; reg < 4; ++reg) {
            const int gr = rowbase + mrow + quad * 4 + reg;
            if (gr < N)
                Yb[(size_t)gr * 128 + nt * 16 + col] = f2bf(acc[nt][reg] + bias[nt]);
        }
    }
}

// ---------------- P0: init cursors -------------------------------------------
__global__ __launch_bounds__(256) void init_cursor_kernel(
    int* __restrict__ cursor1, int* __restrict__ cursor2, int SB_CAP, int NB)
{
    const int i = blockIdx.x * blockDim.x + threadIdx.x;
    if (i < NSB_MAX) cursor1[i] = i * SB_CAP;
    if (i < NB)      cursor2[i] = i * FB_CAP;
}

// ---------------- P1: tile sort by super-bucket, grouped writes --------------
// key layout in pairs1: .x = ((row & 2047) << 17) | col  (super-bucket implied
// by slot region), .y = val bits.
__global__ __launch_bounds__(256) void pass1_kernel(
    const int* __restrict__ rows, const int* __restrict__ cols,
    const float* __restrict__ vals, int* __restrict__ cursor1,
    int2* __restrict__ pairs1, int E)
{
    __shared__ int2 sbuf[TILE];
    __shared__ unsigned char sbin[TILE];
    __shared__ unsigned short perm[TILE];
    __shared__ int hist[NSB_MAX], off[NSB_MAX], gbase[NSB_MAX], cur[NSB_MAX];
    const int t  = threadIdx.x;
    const int lo = blockIdx.x * TILE;
    const int cnt = min(TILE, E - lo);

    if (t < NSB_MAX) hist[t] = 0;
    __syncthreads();
    for (int i = t; i < cnt; i += 256) {
        const int   r = rows[lo + i];
        const int   c = cols[lo + i];
        const float v = vals[lo + i];
        sbuf[i] = make_int2(((r & 2047) << 17) | c, __float_as_int(v));
        const int bb = r >> SB_SHIFT;
        sbin[i] = (unsigned char)bb;
        atomicAdd(&hist[bb], 1);
    }
    __syncthreads();
    if (t == 0) {
        int run = 0;
        for (int k = 0; k < NSB_MAX; ++k) { off[k] = run; cur[k] = run; run += hist[k]; }
    }
    __syncthreads();
    if (t < NSB_MAX && hist[t] > 0) gbase[t] = atomicAdd(&cursor1[t], hist[t]);
    __syncthreads();
    for (int i = t; i < cnt; i += 256) {
        const int pos = atomicAdd(&cur[sbin[i]], 1);
        perm[pos] = (unsigned short)i;
    }
    __syncthreads();
    for (int i = t; i < cnt; i += 256) {
        const int src = perm[i];
        const int bb  = sbin[src];
        pairs1[gbase[bb] + (i - off[bb])] = sbuf[src];
    }
}

// ---------------- P2: chunk sort by fine bucket, grouped writes --------------
__global__ __launch_bounds__(256) void pass2_kernel(
    const int* __restrict__ cursor1, int* __restrict__ cursor2,
    const int2* __restrict__ pairs1, int2* __restrict__ pairs2, int SB_CAP)
{
    __shared__ int2 sbuf[TILE];
    __shared__ unsigned short perm[TILE];
    __shared__ int hist[64], off[64], gbase[64], cur[64];
    const int t   = threadIdx.x;
    const int sb  = blockIdx.x / CH_PER_SB;
    const int ch  = blockIdx.x % CH_PER_SB;
    const int base = sb * SB_CAP;
    const int scnt = cursor1[sb] - base;
    const int csz  = (scnt + CH_PER_SB - 1) / CH_PER_SB;
    const int lo   = ch * csz;
    const int cnt  = max(0, min(csz, scnt - lo));

    if (t < 64) hist[t] = 0;
    __syncthreads();
    for (int i = t; i < cnt; i += 256) {
        const int2 p = pairs1[base + lo + i];
        sbuf[i] = p;
        atomicAdd(&hist[(unsigned)p.x >> 22], 1);   // fine bucket within sb
    }
    __syncthreads();
    if (t == 0) {
        int run = 0;
        for (int k = 0; k < 64; ++k) { off[k] = run; cur[k] = run; run += hist[k]; }
    }
    __syncthreads();
    if (t < 64 && hist[t] > 0)
        gbase[t] = atomicAdd(&cursor2[sb * 64 + t], hist[t]);
    __syncthreads();
    for (int i = t; i < cnt; i += 256) {
        const int pos = atomicAdd(&cur[(unsigned)sbuf[i].x >> 22], 1);
        perm[pos] = (unsigned short)i;
    }
    __syncthreads();
    for (int i = t; i < cnt; i += 256) {
        const int2 p = sbuf[perm[i]];
        const int bb = (unsigned)p.x >> 22;
        // keep ((row&31)<<17)|col for sortgather
        pairs2[gbase[bb] + (i - off[bb])] = make_int2(p.x & 0x3FFFFF, p.y);
    }
}

// ---------------- P3: fused counting-sort (LDS) + 4-edge-wide gather + ELU ---
// Sort phases are thread-per-edge (cheap). Gather loop processes 4 edges per
// wave: lane groups of 16, each group broadcasts one (col,val) and gathers a
// 16B slice of its Y row (dwordx4). Accumulate in 8 regs/lane; row-end
// shfl_xor(32)+shfl_xor(16) reduction; ELU; 512B coalesced store by 16 lanes.
__global__ __launch_bounds__(256) void sortgather_kernel(
    const int* __restrict__ cursor2, const int2* __restrict__ pairs2,
    const unsigned int* __restrict__ Yu, float* __restrict__ out, int N)
{
    __shared__ __align__(16) int2 sbuf[FB_CAP];
    __shared__ __align__(16) int2 dbuf[FB_CAP + 4];
    __shared__ int hist[RPB];
    __shared__ int off[RPB];
    __shared__ int cur[RPB];
    __shared__ int rowtick;
    const int b    = blockIdx.x;
    const int t    = threadIdx.x;
    const int lane = t & 63;
    const int slot = b * FB_CAP;
    int cnt = cursor2[b] - slot;
    if (cnt > FB_CAP) cnt = FB_CAP;

    if (t < RPB) hist[t] = 0;
    if (t == 0) rowtick = 0;
    __syncthreads();
    for (int i = t; i < cnt; i += 256) {
        const int2 p = pairs2[slot + i];
        sbuf[i] = p;
        atomicAdd(&hist[p.x >> 17], 1);
    }
    __syncthreads();
    if (t == 0) {
        int run = 0;
#pragma unroll
        for (int k = 0; k < RPB; ++k) { off[k] = run; cur[k] = run; run += hist[k]; }
    }
    __syncthreads();
    for (int i = t; i < cnt; i += 256) {
        const int2 p   = sbuf[i];
        const int  pos = atomicAdd(&cur[p.x >> 17], 1);
        dbuf[pos] = make_int2(p.x & 0x1FFFF, p.y);
    }
    if (t < 4) dbuf[cnt + t] = make_int2(0, 0);   // pad: tail over-reads hit row 0, v=0
    __syncthreads();

    const int sub   = lane >> 4;   // which of the 4 edges in a chunk
    const int qlane = lane & 15;   // 16 lanes span one 256B Y row (dwordx4 each)

    for (;;) {
        int rl = 0;
        if (lane == 0) rl = atomicAdd(&rowtick, 1);
        rl = __shfl(rl, 0);
        if (rl >= RPB) break;
        const int gr = b * RPB + rl;
        if (gr >= N) continue;
        const int s = off[rl];
        const int e = s + hist[rl];

        float acc0 = 0.f, acc1 = 0.f, acc2 = 0.f, acc3 = 0.f;
        float acc4 = 0.f, acc5 = 0.f, acc6 = 0.f, acc7 = 0.f;
#pragma unroll 2
        for (int j = s; j < e; j += 4) {
            const int2 p = dbuf[j + sub];            // 4 distinct broadcast addrs
            float v = __int_as_float(p.y);
            v = (j + sub < e) ? v : 0.0f;            // mask tail (y stays valid)
            const uint4 y = *(const uint4*)&Yu[((unsigned)p.x << 6) + qlane * 4];
            acc0 = fmaf(v, __uint_as_float(y.x << 16), acc0);
            acc1 = fmaf(v, __uint_as_float(y.x & 0xFFFF0000u), acc1);
            acc2 = fmaf(v, __uint_as_float(y.y << 16), acc2);
            acc3 = fmaf(v, __uint_as_float(y.y & 0xFFFF0000u), acc3);
            acc4 = fmaf(v, __uint_as_float(y.z << 16), acc4);
            acc5 = fmaf(v, __uint_as_float(y.z & 0xFFFF0000u), acc5);
            acc6 = fmaf(v, __uint_as_float(y.w << 16), acc6);
            acc7 = fmaf(v, __uint_as_float(y.w & 0xFFFF0000u), acc7);
        }
        // reduce across the 4 sub-groups (lanes differing in bits 5 and 4)
        acc0 += __shfl_xor(acc0, 32); acc1 += __shfl_xor(acc1, 32);
        acc2 += __shfl_xor(acc2, 32); acc3 += __shfl_xor(acc3, 32);
        acc4 += __shfl_xor(acc4, 32); acc5 += __shfl_xor(acc5, 32);
        acc6 += __shfl_xor(acc6, 32); acc7 += __shfl_xor(acc7, 32);
        acc0 += __shfl_xor(acc0, 16); acc1 += __shfl_xor(acc1, 16);
        acc2 += __shfl_xor(acc2, 16); acc3 += __shfl_xor(acc3, 16);
        acc4 += __shfl_xor(acc4, 16); acc5 += __shfl_xor(acc5, 16);
        acc6 += __shfl_xor(acc6, 16); acc7 += __shfl_xor(acc7, 16);

        if (lane < 16) {
            float4 o0, o1;
            o0.x = acc0 > 0.f ? acc0 : __expf(acc0) - 1.f;
            o0.y = acc1 > 0.f ? acc1 : __expf(acc1) - 1.f;
            o0.z = acc2 > 0.f ? acc2 : __expf(acc2) - 1.f;
            o0.w = acc3 > 0.f ? acc3 : __expf(acc3) - 1.f;
            o1.x = acc4 > 0.f ? acc4 : __expf(acc4) - 1.f;
            o1.y = acc5 > 0.f ? acc5 : __expf(acc5) - 1.f;
            o1.z = acc6 > 0.f ? acc6 : __expf(acc6) - 1.f;
            o1.w = acc7 > 0.f ? acc7 : __expf(acc7) - 1.f;
            float* po = &out[(size_t)gr * 128 + qlane * 8];
            *(float4*)po       = o0;
            *(float4*)(po + 4) = o1;
        }
    }
}

// ---------------- Fallback path (fp32, atomic scatter) -----------------------
__global__ __launch_bounds__(256) void gemm_bias_kernel(
    const float* __restrict__ x, const float* __restrict__ W,
    const float* __restrict__ b, float* __restrict__ Y, int N)
{
    __shared__ float Wt[128][130];
    const int tid  = threadIdx.x;
    const int wave = tid >> 6;
    const int lane = tid & 63;
    for (int i = tid; i < 128 * 128; i += 256) {
        const int o = i >> 7, k = i & 127;
        Wt[k][o] = W[i];
    }
    __syncthreads();
    const float2 bv = *(const float2*)&b[2 * lane];
    for (int row = blockIdx.x * 4 + wave; row < N; row += gridDim.x * 4) {
        float acc0 = 0.f, acc1 = 0.f;
        for (int k = 0; k < 128; ++k) {
            const float2 w = *(const float2*)&Wt[k][2 * lane];
            const float xv = x[(size_t)row * 128 + k];
            acc0 = fmaf(xv, w.x, acc0);
            acc1 = fmaf(xv, w.y, acc1);
        }
        float2 o2; o2.x = acc0 + bv.x; o2.y = acc1 + bv.y;
        *(float2*)&Y[(size_t)row * 128 + 2 * lane] = o2;
    }
}

__global__ __launch_bounds__(256) void scatter_kernel(
    const int* __restrict__ rows, const int* __restrict__ cols,
    const float* __restrict__ vals, const float* __restrict__ Y,
    float* __restrict__ out, int E)
{
    const long long gid = (long long)blockIdx.x * blockDim.x + threadIdx.x;
    const int wid  = (int)(gid >> 6);
    const int lane = threadIdx.x & 63;
    if (wid >= E) return;
    const int   r = rows[wid];
    const int   c = cols[wid];
    const float v = vals[wid];
    const float2 y = *(const float2*)&Y[(size_t)c * 128 + 2 * lane];
    float* po = &out[(size_t)r * 128 + 2 * lane];
    atomicAdd(po,     v * y.x);
    atomicAdd(po + 1, v * y.y);
}

__global__ __launch_bounds__(256) void elu_kernel(float* __restrict__ out, int n4)
{
    int i = blockIdx.x * blockDim.x + threadIdx.x;
    const int stride = gridDim.x * blockDim.x;
    float4* p = (float4*)out;
    for (; i < n4; i += stride) {
        float4 v = p[i];
        v.x = v.x > 0.f ? v.x : expf(v.x) - 1.f;
        v.y = v.y > 0.f ? v.y : expf(v.y) - 1.f;
        v.z = v.z > 0.f ? v.z : expf(v.z) - 1.f;
        v.w = v.w > 0.f ? v.w : expf(v.w) - 1.f;
        p[i] = v;
    }
}

// -----------------------------------------------------------------------------
extern "C" void kernel_launch(void* const* d_in, const int* in_sizes, int n_in,
                              void* d_out, int out_size, void* d_ws, size_t ws_size,
                              hipStream_t stream)
{
    const float* x    = (const float*)d_in[0];
    const float* W    = (const float*)d_in[1];
    const float* b    = (const float*)d_in[2];
    const int*   rows = (const int*)d_in[3];
    const int*   cols = (const int*)d_in[4];
    const float* vals = (const float*)d_in[5];
    float* out = (float*)d_out;

    const int N   = in_sizes[0] / 128;
    const int E   = in_sizes[3];
    const int NB  = (N + RPB - 1) / RPB;               // fine buckets
    const int NSB = (N + (1 << SB_SHIFT) - 1) >> SB_SHIFT;  // super-buckets

    // SB_CAP = mean + ~10 sigma, 64-aligned
    const int sb_mean = (E + NSB - 1) / NSB;
    int sbsig = 1; while (sbsig * sbsig < sb_mean) ++sbsig;
    const int SB_CAP = (sb_mean + 10 * sbsig + 63) & ~63;

    auto align256 = [](size_t v) { return (v + 255) & ~(size_t)255; };
    const size_t offPairs2 = 0;
    const size_t szPairs2  = (size_t)NB * FB_CAP * 8;
    const size_t offShared = align256(offPairs2 + szPairs2);   // pairs1 then Y
    const size_t szShared  = (size_t)NSB * SB_CAP * 8 > (size_t)N * 256
                           ? (size_t)NSB * SB_CAP * 8 : (size_t)N * 256;
    const size_t offCur1   = align256(offShared + szShared);
    const size_t offCur2   = align256(offCur1 + NSB_MAX * 4);
    const size_t need      = offCur2 + (size_t)NB * 4;

    const bool csr_ok = (need <= ws_size) && (NSB <= NSB_MAX) &&
                        ((long long)E <= (long long)NB * 1056) &&
                        (SB_CAP <= CH_PER_SB * TILE);

    if (csr_ok) {
        int2* pairs2        = (int2*)((char*)d_ws + offPairs2);
        int2* pairs1        = (int2*)((char*)d_ws + offShared);
        unsigned short* Yb  = (unsigned short*)((char*)d_ws + offShared);
        int*  cursor1       = (int*)((char*)d_ws + offCur1);
        int*  cursor2       = (int*)((char*)d_ws + offCur2);

        init_cursor_kernel<<<(NB + 255) / 256, 256, 0, stream>>>(cursor1, cursor2,
                                                                 SB_CAP, NB);
        pass1_kernel<<<(E + TILE - 1) / TILE, 256, 0, stream>>>(rows, cols, vals,
                                                                cursor1, pairs1, E);
        pass2_kernel<<<NSB * CH_PER_SB, 256, 0, stream>>>(cursor1, cursor2,
                                                          pairs1, pairs2, SB_CAP);
        // GEMM after pass2: Yb aliases pairs1 (dead now)
        gemm_mfma_kernel<<<(N + 63) / 64, 256, 0, stream>>>(x, W, b, Yb, N);
        sortgather_kernel<<<NB, 256, 0, stream>>>(cursor2, pairs2,
                                                  (const unsigned int*)Yb, out, N);
    } else {
        float* Y = (float*)d_ws;
        hipMemsetAsync(d_out, 0, (size_t)out_size * sizeof(float), stream);
        gemm_bias_kernel<<<512, 256, 0, stream>>>(x, W, b, Y, N);
        scatter_kernel<<<(E + 3) / 4, 256, 0, stream>>>(rows, cols, vals, Y, out, E);
        elu_kernel<<<1024, 256, 0, stream>>>(out, out_size / 4);
    }
}

// Round 3
// 312.523 us; speedup vs baseline: 7.6680x; 1.0149x over previous
//
#include <hip/hip_runtime.h>
#include <hip/hip_bf16.h>
#include <cmath>

#define RPB      32        // rows per fine bucket
#define FB_CAP   1280      // fine-bucket slot capacity (mean 1024, +8 sigma)
#define SB_SHIFT 11        // 2048 rows per super-bucket
#define NSB_MAX  64
#define TILE     2048      // edges per binning tile
#define CH_PER_SB 34       // pass-2 chunks per super-bucket (cap/34 <= TILE)

typedef __attribute__((ext_vector_type(8))) short short8;
typedef __attribute__((ext_vector_type(4))) float floatx4;

__device__ __forceinline__ unsigned short f2bf(float f) {
    unsigned int u = __float_as_uint(f);
    u += 0x7FFFu + ((u >> 16) & 1u);   // RNE
    return (unsigned short)(u >> 16);
}

// ---------------- MFMA GEMM: Yb[n][o] = bf16( x@W^T + b ) --------------------
__global__ __launch_bounds__(256) void gemm_mfma_kernel(
    const float* __restrict__ x, const float* __restrict__ W,
    const float* __restrict__ b, unsigned short* __restrict__ Yb, int N)
{
    __shared__ unsigned short Wb[128][136];
    __shared__ unsigned short Xb[64][136];
    const int t    = threadIdx.x;
    const int wave = t >> 6;
    const int lane = t & 63;
    const int col  = lane & 15;
    const int quad = lane >> 4;
    const int rowbase = blockIdx.x * 64;

#pragma unroll
    for (int i = 0; i < 16; ++i) {
        const int idx = t + 256 * i;
        const int o = idx >> 5, k4 = (idx & 31) * 4;
        const float4 v = *(const float4*)&W[(size_t)idx * 4];
        Wb[o][k4 + 0] = f2bf(v.x); Wb[o][k4 + 1] = f2bf(v.y);
        Wb[o][k4 + 2] = f2bf(v.z); Wb[o][k4 + 3] = f2bf(v.w);
    }
#pragma unroll
    for (int i = 0; i < 8; ++i) {
        const int idx = t + 256 * i;
        const int row = idx >> 5, k4 = (idx & 31) * 4;
        const int gr = rowbase + row;
        float4 v = make_float4(0.f, 0.f, 0.f, 0.f);
        if (gr < N) v = *(const float4*)&x[(size_t)gr * 128 + k4];
        Xb[row][k4 + 0] = f2bf(v.x); Xb[row][k4 + 1] = f2bf(v.y);
        Xb[row][k4 + 2] = f2bf(v.z); Xb[row][k4 + 3] = f2bf(v.w);
    }
    __syncthreads();

    float bias[8];
#pragma unroll
    for (int nt = 0; nt < 8; ++nt) bias[nt] = b[nt * 16 + col];

    floatx4 acc[8] = {};
    const int mrow = wave * 16;
#pragma unroll
    for (int k0 = 0; k0 < 128; k0 += 32) {
        const short8 a = *(const short8*)&Xb[mrow + col][k0 + quad * 8];
#pragma unroll
        for (int nt = 0; nt < 8; ++nt) {
            const short8 bf = *(const short8*)&Wb[nt * 16 + col][k0 + quad * 8];
            acc[nt] = __builtin_amdgcn_mfma_f32_16x16x32_bf16(a, bf, acc[nt], 0, 0, 0);
        }
    }
#pragma unroll
    for (int nt = 0; nt < 8; ++nt) {
#pragma unroll
        for (int reg = 0; reg < 4; ++reg) {
            const int gr = rowbase + mrow + quad * 4 + reg;
            if (gr < N)
                Yb[(size_t)gr * 128 + nt * 16 + col] = f2bf(acc[nt][reg] + bias[nt]);
        }
    }
}

// ---------------- P0: init cursors -------------------------------------------
__global__ __launch_bounds__(256) void init_cursor_kernel(
    int* __restrict__ cursor1, int* __restrict__ cursor2, int SB_CAP, int NB)
{
    const int i = blockIdx.x * blockDim.x + threadIdx.x;
    if (i < NSB_MAX) cursor1[i] = i * SB_CAP;
    if (i < NB)      cursor2[i] = i * FB_CAP;
}

// ---------------- P1: tile sort by super-bucket, grouped writes --------------
// key layout in pairs1: .x = ((row & 2047) << 17) | col  (super-bucket implied
// by slot region), .y = val bits.
__global__ __launch_bounds__(256) void pass1_kernel(
    const int* __restrict__ rows, const int* __restrict__ cols,
    const float* __restrict__ vals, int* __restrict__ cursor1,
    int2* __restrict__ pairs1, int E)
{
    __shared__ int2 sbuf[TILE];
    __shared__ unsigned char sbin[TILE];
    __shared__ unsigned short perm[TILE];
    __shared__ int hist[NSB_MAX], off[NSB_MAX], gbase[NSB_MAX], cur[NSB_MAX];
    const int t  = threadIdx.x;
    const int lane = t & 63;
    const int lo = blockIdx.x * TILE;
    const int cnt = min(TILE, E - lo);

    if (t < NSB_MAX) hist[t] = 0;
    __syncthreads();
    for (int i = t; i < cnt; i += 256) {
        const int   r = rows[lo + i];
        const int   c = cols[lo + i];
        const float v = vals[lo + i];
        sbuf[i] = make_int2(((r & 2047) << 17) | c, __float_as_int(v));
        const int bb = r >> SB_SHIFT;
        sbin[i] = (unsigned char)bb;
        atomicAdd(&hist[bb], 1);
    }
    __syncthreads();
    if (t < NSB_MAX) {                       // wave-0 parallel exclusive scan
        const int h = hist[t];
        int s = h;
#pragma unroll
        for (int d = 1; d < NSB_MAX; d <<= 1) {
            const int n = __shfl_up(s, d);
            if (lane >= d) s += n;
        }
        off[t] = s - h;
        cur[t] = s - h;
        if (h > 0) gbase[t] = atomicAdd(&cursor1[t], h);
    }
    __syncthreads();
    for (int i = t; i < cnt; i += 256) {
        const int pos = atomicAdd(&cur[sbin[i]], 1);
        perm[pos] = (unsigned short)i;
    }
    __syncthreads();
    for (int i = t; i < cnt; i += 256) {
        const int src = perm[i];
        const int bb  = sbin[src];
        pairs1[gbase[bb] + (i - off[bb])] = sbuf[src];
    }
}

// ---------------- P2: chunk sort by fine bucket, grouped writes --------------
__global__ __launch_bounds__(256) void pass2_kernel(
    const int* __restrict__ cursor1, int* __restrict__ cursor2,
    const int2* __restrict__ pairs1, int2* __restrict__ pairs2, int SB_CAP)
{
    __shared__ int2 sbuf[TILE];
    __shared__ unsigned short perm[TILE];
    __shared__ int hist[64], off[64], gbase[64], cur[64];
    const int t   = threadIdx.x;
    const int lane = t & 63;
    const int sb  = blockIdx.x / CH_PER_SB;
    const int ch  = blockIdx.x % CH_PER_SB;
    const int base = sb * SB_CAP;
    const int scnt = cursor1[sb] - base;
    const int csz  = (scnt + CH_PER_SB - 1) / CH_PER_SB;
    const int lo   = ch * csz;
    const int cnt  = max(0, min(csz, scnt - lo));

    if (t < 64) hist[t] = 0;
    __syncthreads();
    for (int i = t; i < cnt; i += 256) {
        const int2 p = pairs1[base + lo + i];
        sbuf[i] = p;
        atomicAdd(&hist[(unsigned)p.x >> 22], 1);   // fine bucket within sb
    }
    __syncthreads();
    if (t < 64) {                            // wave-0 parallel exclusive scan
        const int h = hist[t];
        int s = h;
#pragma unroll
        for (int d = 1; d < 64; d <<= 1) {
            const int n = __shfl_up(s, d);
            if (lane >= d) s += n;
        }
        off[t] = s - h;
        cur[t] = s - h;
        if (h > 0) gbase[t] = atomicAdd(&cursor2[sb * 64 + t], h);
    }
    __syncthreads();
    for (int i = t; i < cnt; i += 256) {
        const int pos = atomicAdd(&cur[(unsigned)sbuf[i].x >> 22], 1);
        perm[pos] = (unsigned short)i;
    }
    __syncthreads();
    for (int i = t; i < cnt; i += 256) {
        const int2 p = sbuf[perm[i]];
        const int bb = (unsigned)p.x >> 22;
        // keep ((row&31)<<17)|col for sortgather
        pairs2[gbase[bb] + (i - off[bb])] = make_int2(p.x & 0x3FFFFF, p.y);
    }
}

// ---------------- P3: fused counting-sort (LDS) + 8-edge-wide gather + ELU ---
// Static row ownership (wave w -> rows 8w..8w+7, no rowtick atomic). Gather
// loop: 16-lane groups handle edges j+sub and j+4+sub per iteration -> 2
// independent dwordx4 gathers/iter, unroll 2 -> 4 loads in flight per wave.
__global__ __launch_bounds__(256) void sortgather_kernel(
    const int* __restrict__ cursor2, const int2* __restrict__ pairs2,
    const unsigned int* __restrict__ Yu, float* __restrict__ out, int N)
{
    __shared__ __align__(16) int2 sbuf[FB_CAP];
    __shared__ __align__(16) int2 dbuf[FB_CAP + 8];
    __shared__ int hist[RPB];
    __shared__ int off[RPB];
    __shared__ int cur[RPB];
    const int b    = blockIdx.x;
    const int t    = threadIdx.x;
    const int w    = t >> 6;
    const int lane = t & 63;
    const int slot = b * FB_CAP;
    int cnt = cursor2[b] - slot;
    if (cnt > FB_CAP) cnt = FB_CAP;

    if (t < RPB) hist[t] = 0;
    __syncthreads();
    for (int i = t; i < cnt; i += 256) {
        const int2 p = pairs2[slot + i];
        sbuf[i] = p;
        atomicAdd(&hist[p.x >> 17], 1);
    }
    __syncthreads();
    if (t < RPB) {                           // wave-0 parallel exclusive scan
        const int h = hist[t];
        int s = h;
#pragma unroll
        for (int d = 1; d < RPB; d <<= 1) {
            const int n = __shfl_up(s, d);
            if (lane >= d) s += n;
        }
        off[t] = s - h;
        cur[t] = s - h;
    }
    __syncthreads();
    for (int i = t; i < cnt; i += 256) {
        const int2 p   = sbuf[i];
        const int  pos = atomicAdd(&cur[p.x >> 17], 1);
        dbuf[pos] = make_int2(p.x & 0x1FFFF, p.y);
    }
    if (t < 8) dbuf[cnt + t] = make_int2(0, 0);   // pad: tail over-reads hit row 0, v=0
    __syncthreads();

    const int sub   = lane >> 4;   // which edge of the group-of-4 this 16-lane group takes
    const int qlane = lane & 15;   // 16 lanes span one 256B Y row (dwordx4 each)

#pragma unroll
    for (int k = 0; k < RPB / 4; ++k) {
        const int rl = w * (RPB / 4) + k;    // static: wave w owns 8 rows
        const int gr = b * RPB + rl;
        const int s = off[rl];
        const int e = s + hist[rl];

        float acc0 = 0.f, acc1 = 0.f, acc2 = 0.f, acc3 = 0.f;
        float acc4 = 0.f, acc5 = 0.f, acc6 = 0.f, acc7 = 0.f;
#pragma unroll 2
        for (int j = s; j < e; j += 8) {
            const int2 pA = dbuf[j + sub];          // 4 broadcast addrs
            const int2 pB = dbuf[j + 4 + sub];      // next 4 (pad keeps in-bounds)
            float vA = __int_as_float(pA.y);
            float vB = __int_as_float(pB.y);
            vA = (j + sub < e)     ? vA : 0.0f;     // mask tail (addr stays valid)
            vB = (j + 4 + sub < e) ? vB : 0.0f;
            const uint4 yA = *(const uint4*)&Yu[((unsigned)pA.x << 6) + qlane * 4];
            const uint4 yB = *(const uint4*)&Yu[((unsigned)pB.x << 6) + qlane * 4];
            acc0 = fmaf(vA, __uint_as_float(yA.x << 16), acc0);
            acc1 = fmaf(vA, __uint_as_float(yA.x & 0xFFFF0000u), acc1);
            acc2 = fmaf(vA, __uint_as_float(yA.y << 16), acc2);
            acc3 = fmaf(vA, __uint_as_float(yA.y & 0xFFFF0000u), acc3);
            acc4 = fmaf(vA, __uint_as_float(yA.z << 16), acc4);
            acc5 = fmaf(vA, __uint_as_float(yA.z & 0xFFFF0000u), acc5);
            acc6 = fmaf(vA, __uint_as_float(yA.w << 16), acc6);
            acc7 = fmaf(vA, __uint_as_float(yA.w & 0xFFFF0000u), acc7);
            acc0 = fmaf(vB, __uint_as_float(yB.x << 16), acc0);
            acc1 = fmaf(vB, __uint_as_float(yB.x & 0xFFFF0000u), acc1);
            acc2 = fmaf(vB, __uint_as_float(yB.y << 16), acc2);
            acc3 = fmaf(vB, __uint_as_float(yB.y & 0xFFFF0000u), acc3);
            acc4 = fmaf(vB, __uint_as_float(yB.z << 16), acc4);
            acc5 = fmaf(vB, __uint_as_float(yB.z & 0xFFFF0000u), acc5);
            acc6 = fmaf(vB, __uint_as_float(yB.w << 16), acc6);
            acc7 = fmaf(vB, __uint_as_float(yB.w & 0xFFFF0000u), acc7);
        }
        // reduce across the 4 sub-groups (lanes differing in bits 5 and 4)
        acc0 += __shfl_xor(acc0, 32); acc1 += __shfl_xor(acc1, 32);
        acc2 += __shfl_xor(acc2, 32); acc3 += __shfl_xor(acc3, 32);
        acc4 += __shfl_xor(acc4, 32); acc5 += __shfl_xor(acc5, 32);
        acc6 += __shfl_xor(acc6, 32); acc7 += __shfl_xor(acc7, 32);
        acc0 += __shfl_xor(acc0, 16); acc1 += __shfl_xor(acc1, 16);
        acc2 += __shfl_xor(acc2, 16); acc3 += __shfl_xor(acc3, 16);
        acc4 += __shfl_xor(acc4, 16); acc5 += __shfl_xor(acc5, 16);
        acc6 += __shfl_xor(acc6, 16); acc7 += __shfl_xor(acc7, 16);

        if (lane < 16 && gr < N) {
            float4 o0, o1;
            o0.x = acc0 > 0.f ? acc0 : __expf(acc0) - 1.f;
            o0.y = acc1 > 0.f ? acc1 : __expf(acc1) - 1.f;
            o0.z = acc2 > 0.f ? acc2 : __expf(acc2) - 1.f;
            o0.w = acc3 > 0.f ? acc3 : __expf(acc3) - 1.f;
            o1.x = acc4 > 0.f ? acc4 : __expf(acc4) - 1.f;
            o1.y = acc5 > 0.f ? acc5 : __expf(acc5) - 1.f;
            o1.z = acc6 > 0.f ? acc6 : __expf(acc6) - 1.f;
            o1.w = acc7 > 0.f ? acc7 : __expf(acc7) - 1.f;
            float* po = &out[(size_t)gr * 128 + qlane * 8];
            *(float4*)po       = o0;
            *(float4*)(po + 4) = o1;
        }
    }
}

// ---------------- Fallback path (fp32, atomic scatter) -----------------------
__global__ __launch_bounds__(256) void gemm_bias_kernel(
    const float* __restrict__ x, const float* __restrict__ W,
    const float* __restrict__ b, float* __restrict__ Y, int N)
{
    __shared__ float Wt[128][130];
    const int tid  = threadIdx.x;
    const int wave = tid >> 6;
    const int lane = tid & 63;
    for (int i = tid; i < 128 * 128; i += 256) {
        const int o = i >> 7, k = i & 127;
        Wt[k][o] = W[i];
    }
    __syncthreads();
    const float2 bv = *(const float2*)&b[2 * lane];
    for (int row = blockIdx.x * 4 + wave; row < N; row += gridDim.x * 4) {
        float acc0 = 0.f, acc1 = 0.f;
        for (int k = 0; k < 128; ++k) {
            const float2 w = *(const float2*)&Wt[k][2 * lane];
            const float xv = x[(size_t)row * 128 + k];
            acc0 = fmaf(xv, w.x, acc0);
            acc1 = fmaf(xv, w.y, acc1);
        }
        float2 o2; o2.x = acc0 + bv.x; o2.y = acc1 + bv.y;
        *(float2*)&Y[(size_t)row * 128 + 2 * lane] = o2;
    }
}

__global__ __launch_bounds__(256) void scatter_kernel(
    const int* __restrict__ rows, const int* __restrict__ cols,
    const float* __restrict__ vals, const float* __restrict__ Y,
    float* __restrict__ out, int E)
{
    const long long gid = (long long)blockIdx.x * blockDim.x + threadIdx.x;
    const int wid  = (int)(gid >> 6);
    const int lane = threadIdx.x & 63;
    if (wid >= E) return;
    const int   r = rows[wid];
    const int   c = cols[wid];
    const float v = vals[wid];
    const float2 y = *(const float2*)&Y[(size_t)c * 128 + 2 * lane];
    float* po = &out[(size_t)r * 128 + 2 * lane];
    atomicAdd(po,     v * y.x);
    atomicAdd(po + 1, v * y.y);
}

__global__ __launch_bounds__(256) void elu_kernel(float* __restrict__ out, int n4)
{
    int i = blockIdx.x * blockDim.x + threadIdx.x;
    const int stride = gridDim.x * blockDim.x;
    float4* p = (float4*)out;
    for (; i < n4; i += stride) {
        float4 v = p[i];
        v.x = v.x > 0.f ? v.x : expf(v.x) - 1.f;
        v.y = v.y > 0.f ? v.y : expf(v.y) - 1.f;
        v.z = v.z > 0.f ? v.z : expf(v.z) - 1.f;
        v.w = v.w > 0.f ? v.w : expf(v.w) - 1.f;
        p[i] = v;
    }
}

// -----------------------------------------------------------------------------
extern "C" void kernel_launch(void* const* d_in, const int* in_sizes, int n_in,
                              void* d_out, int out_size, void* d_ws, size_t ws_size,
                              hipStream_t stream)
{
    const float* x    = (const float*)d_in[0];
    const float* W    = (const float*)d_in[1];
    const float* b    = (const float*)d_in[2];
    const int*   rows = (const int*)d_in[3];
    const int*   cols = (const int*)d_in[4];
    const float* vals = (const float*)d_in[5];
    float* out = (float*)d_out;

    const int N   = in_sizes[0] / 128;
    const int E   = in_sizes[3];
    const int NB  = (N + RPB - 1) / RPB;               // fine buckets
    const int NSB = (N + (1 << SB_SHIFT) - 1) >> SB_SHIFT;  // super-buckets

    // SB_CAP = mean + ~10 sigma, 64-aligned
    const int sb_mean = (E + NSB - 1) / NSB;
    int sbsig = 1; while (sbsig * sbsig < sb_mean) ++sbsig;
    const int SB_CAP = (sb_mean + 10 * sbsig + 63) & ~63;

    auto align256 = [](size_t v) { return (v + 255) & ~(size_t)255; };
    const size_t offPairs2 = 0;
    const size_t szPairs2  = (size_t)NB * FB_CAP * 8;
    const size_t offShared = align256(offPairs2 + szPairs2);   // pairs1 then Y
    const size_t szShared  = (size_t)NSB * SB_CAP * 8 > (size_t)N * 256
                           ? (size_t)NSB * SB_CAP * 8 : (size_t)N * 256;
    const size_t offCur1   = align256(offShared + szShared);
    const size_t offCur2   = align256(offCur1 + NSB_MAX * 4);
    const size_t need      = offCur2 + (size_t)NB * 4;

    const bool csr_ok = (need <= ws_size) && (NSB <= NSB_MAX) &&
                        ((long long)E <= (long long)NB * 1056) &&
                        (SB_CAP <= CH_PER_SB * TILE);

    if (csr_ok) {
        int2* pairs2        = (int2*)((char*)d_ws + offPairs2);
        int2* pairs1        = (int2*)((char*)d_ws + offShared);
        unsigned short* Yb  = (unsigned short*)((char*)d_ws + offShared);
        int*  cursor1       = (int*)((char*)d_ws + offCur1);
        int*  cursor2       = (int*)((char*)d_ws + offCur2);

        init_cursor_kernel<<<(NB + 255) / 256, 256, 0, stream>>>(cursor1, cursor2,
                                                                 SB_CAP, NB);
        pass1_kernel<<<(E + TILE - 1) / TILE, 256, 0, stream>>>(rows, cols, vals,
                                                                cursor1, pairs1, E);
        pass2_kernel<<<NSB * CH_PER_SB, 256, 0, stream>>>(cursor1, cursor2,
                                                          pairs1, pairs2, SB_CAP);
        // GEMM after pass2: Yb aliases pairs1 (dead now)
        gemm_mfma_kernel<<<(N + 63) / 64, 256, 0, stream>>>(x, W, b, Yb, N);
        sortgather_kernel<<<NB, 256, 0, stream>>>(cursor2, pairs2,
                                                  (const unsigned int*)Yb, out, N);
    } else {
        float* Y = (float*)d_ws;
        hipMemsetAsync(d_out, 0, (size_t)out_size * sizeof(float), stream);
        gemm_bias_kernel<<<512, 256, 0, stream>>>(x, W, b, Y, N);
        scatter_kernel<<<(E + 3) / 4, 256, 0, stream>>>(rows, cols, vals, Y, out, E);
        elu_kernel<<<1024, 256, 0, stream>>>(out, out_size / 4);
    }
}